// Round 7
// baseline (550.517 us; speedup 1.0000x reference)
//
#include <hip/hip_runtime.h>
#include <hip/hip_bf16.h>

#define HID 2048
#define NH 20
#define QR 768
#define KVR 512
#define DN 192
#define DR 64
#define DV 256
#define HD 256          // HEAD_DIM = DN + DR
#define S_LEN 2048
#define HKV 448         // DN + DV
#define KV_N (NH * HKV) // 8960
#define Q_N (NH * HD)   // 5120
#define O_N (NH * DV)   // 5120
#define KVA_N (KVR + DR) // 576
#define KVAP 640         // padded kv_a rows
#define QKVA (QR + KVAP) // 1408 fused a-proj cols

typedef short bf16x8 __attribute__((ext_vector_type(8)));
typedef short bf16x4 __attribute__((ext_vector_type(4)));
typedef float f32x4 __attribute__((ext_vector_type(4)));

__device__ inline short f2bs(float f) {
  __hip_bfloat16 h = __float2bfloat16(f);
  return *reinterpret_cast<short*>(&h);
}
__device__ inline float bs2f(short s) {
  __hip_bfloat16 h = *reinterpret_cast<__hip_bfloat16*>(&s);
  return __bfloat162float(h);
}

__device__ inline void gload16(const void* g, void* l) {
  __builtin_amdgcn_global_load_lds((const __attribute__((address_space(1))) void*)g,
                                   (__attribute__((address_space(3))) void*)l, 16, 0, 0);
}

#define WAIT_LGKM0() asm volatile("s_waitcnt lgkmcnt(0)" ::: "memory")
#define WAIT_VM0() asm volatile("s_waitcnt vmcnt(0)" ::: "memory")

// ---------------- fp32 -> bf16 convert ----------------
__global__ void f2b_kernel(const float* __restrict__ in, short* __restrict__ out, size_t n) {
  size_t i = (size_t)blockIdx.x * blockDim.x + threadIdx.x;
  size_t stride = (size_t)gridDim.x * blockDim.x;
  for (; i < n; i += stride) out[i] = f2bs(in[i]);
}

// ---------------- big GEMM: 128x128 tile, BK=64, global_load_lds + XOR swizzle ----------------
template <int OUT_BF16>
__global__ __launch_bounds__(256) void gemm128(const short* __restrict__ A,
                                               const short* __restrict__ B,
                                               void* __restrict__ Cp,
                                               int M, int N, int K) {
  __shared__ alignas(16) short As[128 * 64];
  __shared__ alignas(16) short Bs[128 * 64];
  int tid = threadIdx.x;
  int w = tid >> 6, l = tid & 63;
  int lr = l & 15, lg = l >> 4;
  int wr = w >> 1, wc = w & 1;
  int row0 = blockIdx.y * 128, col0 = blockIdx.x * 128;
  f32x4 acc[4][4] = {};
  for (int k0 = 0; k0 < K; k0 += 64) {
    if (k0) __syncthreads();
#pragma unroll
    for (int p = 0; p < 4; ++p) {
      int c = p * 256 + tid;
      int row = c >> 3;
      int sb = ((c & 7) * 16) ^ ((row & 7) << 4);
      gload16((const char*)A + ((size_t)(row0 + row) * K + k0) * 2 + sb, (char*)As + c * 16);
      gload16((const char*)B + ((size_t)(col0 + row) * K + k0) * 2 + sb, (char*)Bs + c * 16);
    }
    __syncthreads();
    bf16x8 af[4][2], bf[4][2];
#pragma unroll
    for (int m = 0; m < 4; ++m)
#pragma unroll
      for (int kk = 0; kk < 2; ++kk) {
        int ra = wr * 64 + m * 16 + lr;
        int rb = wc * 64 + m * 16 + lr;
        int cb = kk * 64 + lg * 16;
        af[m][kk] = *(const bf16x8*)((const char*)As + ra * 128 + (cb ^ ((ra & 7) << 4)));
        bf[m][kk] = *(const bf16x8*)((const char*)Bs + rb * 128 + (cb ^ ((rb & 7) << 4)));
      }
#pragma unroll
    for (int m = 0; m < 4; ++m)
#pragma unroll
      for (int n = 0; n < 4; ++n) {
        acc[m][n] = __builtin_amdgcn_mfma_f32_16x16x32_bf16(af[m][0], bf[n][0], acc[m][n], 0, 0, 0);
        acc[m][n] = __builtin_amdgcn_mfma_f32_16x16x32_bf16(af[m][1], bf[n][1], acc[m][n], 0, 0, 0);
      }
  }
#pragma unroll
  for (int m = 0; m < 4; ++m)
#pragma unroll
    for (int n = 0; n < 4; ++n)
#pragma unroll
      for (int r = 0; r < 4; ++r) {
        int row = row0 + wr * 64 + m * 16 + lg * 4 + r;
        int col = col0 + wc * 64 + n * 16 + lr;
        if (OUT_BF16)
          ((short*)Cp)[(size_t)row * N + col] = f2bs(acc[m][n][r]);
        else
          ((float*)Cp)[(size_t)row * N + col] = acc[m][n][r];
      }
}

// ---------------- medium GEMM: 64x128 tile (for wide-short shapes) ----------------
__global__ __launch_bounds__(256) void gemm64(const short* __restrict__ A,
                                              const short* __restrict__ B,
                                              float* __restrict__ C,
                                              int M, int N, int K) {
  __shared__ alignas(16) short As[64 * 64];    // 8KB
  __shared__ alignas(16) short Bs[128 * 64];   // 16KB
  int tid = threadIdx.x;
  int w = tid >> 6, l = tid & 63;
  int lr = l & 15, lg = l >> 4;
  int wr = w >> 1, wc = w & 1;
  int row0 = blockIdx.y * 64, col0 = blockIdx.x * 128;
  f32x4 acc[2][4] = {};
  for (int k0 = 0; k0 < K; k0 += 64) {
    if (k0) __syncthreads();
#pragma unroll
    for (int p = 0; p < 2; ++p) {
      int c = p * 256 + tid;
      int row = c >> 3;
      int sb = ((c & 7) * 16) ^ ((row & 7) << 4);
      gload16((const char*)A + ((size_t)(row0 + row) * K + k0) * 2 + sb, (char*)As + c * 16);
    }
#pragma unroll
    for (int p = 0; p < 4; ++p) {
      int c = p * 256 + tid;
      int row = c >> 3;
      int sb = ((c & 7) * 16) ^ ((row & 7) << 4);
      gload16((const char*)B + ((size_t)(col0 + row) * K + k0) * 2 + sb, (char*)Bs + c * 16);
    }
    __syncthreads();
    bf16x8 af[2][2], bf[4][2];
#pragma unroll
    for (int m = 0; m < 2; ++m)
#pragma unroll
      for (int kk = 0; kk < 2; ++kk) {
        int ra = wr * 32 + m * 16 + lr;
        int cb = kk * 64 + lg * 16;
        af[m][kk] = *(const bf16x8*)((const char*)As + ra * 128 + (cb ^ ((ra & 7) << 4)));
      }
#pragma unroll
    for (int n = 0; n < 4; ++n)
#pragma unroll
      for (int kk = 0; kk < 2; ++kk) {
        int rb = wc * 64 + n * 16 + lr;
        int cb = kk * 64 + lg * 16;
        bf[n][kk] = *(const bf16x8*)((const char*)Bs + rb * 128 + (cb ^ ((rb & 7) << 4)));
      }
#pragma unroll
    for (int m = 0; m < 2; ++m)
#pragma unroll
      for (int n = 0; n < 4; ++n) {
        acc[m][n] = __builtin_amdgcn_mfma_f32_16x16x32_bf16(af[m][0], bf[n][0], acc[m][n], 0, 0, 0);
        acc[m][n] = __builtin_amdgcn_mfma_f32_16x16x32_bf16(af[m][1], bf[n][1], acc[m][n], 0, 0, 0);
      }
  }
#pragma unroll
  for (int m = 0; m < 2; ++m)
#pragma unroll
    for (int n = 0; n < 4; ++n)
#pragma unroll
      for (int r = 0; r < 4; ++r) {
        int row = row0 + wr * 32 + m * 16 + lg * 4 + r;
        int col = col0 + wc * 64 + n * 16 + lr;
        C[(size_t)row * N + col] = acc[m][n][r];
      }
}

// ---------------- rmsnorm (fp32 in, bf16 out) ----------------
__global__ __launch_bounds__(256) void rmsnorm_kernel(const float* __restrict__ in,
                                                      const float* __restrict__ w,
                                                      short* __restrict__ out,
                                                      int N, int in_stride, int out_stride) {
  int row = blockIdx.x;
  const float* x = in + (size_t)row * in_stride;
  float ss = 0.f;
  for (int i = threadIdx.x; i < N; i += 256) { float v = x[i]; ss += v * v; }
#pragma unroll
  for (int off = 32; off >= 1; off >>= 1) ss += __shfl_down(ss, off);
  __shared__ float red[4];
  if ((threadIdx.x & 63) == 0) red[threadIdx.x >> 6] = ss;
  __syncthreads();
  float tot = red[0] + red[1] + red[2] + red[3];
  float sc = rsqrtf(tot / (float)N + 1e-5f);
  short* o = out + (size_t)row * out_stride;
  for (int i = threadIdx.x; i < N; i += 256) o[i] = f2bs(x[i] * sc * w[i]);
}

// ---------------- rope tables ----------------
__global__ void rope_table_kernel(const int* __restrict__ pos, float* __restrict__ ct,
                                  float* __restrict__ st) {
  int s = blockIdx.x * blockDim.x + threadIdx.x;
  if (s >= S_LEN) return;
  double p = (double)pos[s];
  for (int d = 0; d < 32; ++d) {
    double invf = exp(-((double)(2 * d) / 64.0) * log(1.0e6));
    double a = p * invf;
    ct[s * 32 + d] = (float)cos(a);
    st[s * 32 + d] = (float)sin(a);
  }
}

// ---------------- rope applied in-place to q's rope slice ----------------
__global__ void rope_q_kernel(short* __restrict__ q, const float* __restrict__ ct,
                              const float* __restrict__ st) {
  int idx = blockIdx.x * blockDim.x + threadIdx.x;
  if (idx >= S_LEN * NH) return;
  int s = idx / NH, h = idx % NH;
  short* p = q + (size_t)s * Q_N + h * HD + DN;
  float x[64];
#pragma unroll
  for (int i = 0; i < 64; ++i) x[i] = bs2f(p[i]);
  const float* c = ct + s * 32;
  const float* sn = st + s * 32;
#pragma unroll
  for (int d = 0; d < 32; ++d) {
    float x1 = x[2 * d], x2 = x[2 * d + 1];
    p[d] = f2bs(x1 * c[d] - x2 * sn[d]);
    p[32 + d] = f2bs(x1 * sn[d] + x2 * c[d]);
  }
}

// ---------------- rope for shared k_rope (reads fused qkv buffer) ----------------
__global__ void rope_k_kernel(const float* __restrict__ base, const float* __restrict__ ct,
                              const float* __restrict__ st, short* __restrict__ kr) {
  int s = blockIdx.x * blockDim.x + threadIdx.x;
  if (s >= S_LEN) return;
  const float* x = base + (size_t)s * QKVA;
  const float* c = ct + s * 32;
  const float* sn = st + s * 32;
  short* o = kr + s * 64;
#pragma unroll
  for (int d = 0; d < 32; ++d) {
    float x1 = x[2 * d], x2 = x[2 * d + 1];
    o[d] = f2bs(x1 * c[d] - x2 * sn[d]);
    o[32 + d] = f2bs(x1 * sn[d] + x2 * c[d]);
  }
}

// ---------------- build Kc[h][s][256] = k_nope ‖ roped k_rope ----------------
__global__ void kc_build(const short* __restrict__ kvx, const short* __restrict__ kr,
                         short* __restrict__ kc) {
  int idx = blockIdx.x * 256 + threadIdx.x;
  int h = idx >> 16;
  int r = idx & 65535;
  int s = r >> 5, c = r & 31;
  const short* src = (c < 24) ? kvx + (size_t)s * KV_N + h * HKV + c * 8
                              : kr + (size_t)s * 64 + (c - 24) * 8;
  *(bf16x8*)(kc + ((size_t)h * S_LEN + s) * HD + c * 8) = *(const bf16x8*)src;
}

// ---------------- transpose V: Vt[h][d][s] ----------------
__global__ __launch_bounds__(256) void vtrans(const short* __restrict__ kvx,
                                              short* __restrict__ vtg) {
  __shared__ short tile[64][65];
  int s0 = blockIdx.x * 64, d0 = blockIdx.y * 64, h = blockIdx.z;
  int tid = threadIdx.x;
#pragma unroll
  for (int p = 0; p < 2; ++p) {
    int s = p * 32 + (tid >> 3), dc = (tid & 7) * 8;
    bf16x8 v = *(const bf16x8*)(kvx + (size_t)(s0 + s) * KV_N + h * HKV + DN + d0 + dc);
#pragma unroll
    for (int j = 0; j < 8; ++j) tile[s][dc + j] = v[j];
  }
  __syncthreads();
#pragma unroll
  for (int p = 0; p < 2; ++p) {
    int d = p * 32 + (tid >> 3), sc = (tid & 7) * 8;
    bf16x8 o;
#pragma unroll
    for (int j = 0; j < 8; ++j) o[j] = tile[sc + j][d];
    *(bf16x8*)(vtg + ((size_t)h * DV + d0 + d) * S_LEN + s0 + sc) = o;
  }
}

// ---------------- fused flash attention v6: swapped QK^T + split-K=2 ----------------
// grid = 1280 (XCD-swizzled -> (half,h,qblk)); 256 thr; KVBLK=32; LDS 32KB -> 5 blocks/CU.
// Each block handles 1024 keys, writes unnormalized fp32 partial acc + (m, lsum).
// V swizzle key = (d ^ (d>>2)) & 3 (2-way/free; old d&3 was 4-way).
__global__ __launch_bounds__(256, 4) void attn6(const short* __restrict__ q,
                                                const short* __restrict__ kc,
                                                const short* __restrict__ vtg,
                                                float* __restrict__ pacc,
                                                float* __restrict__ pm,
                                                float* __restrict__ pl) {
  __shared__ alignas(16) short ks[32 * 256];   // 16KB, 512B rows, 3-bit src XOR
  __shared__ alignas(16) short vt[256 * 32];   // 16KB, vt[d][key], 64B rows
  int bid = blockIdx.x;
  int swz = (bid & 7) * 160 + (bid >> 3);      // 1280 = 8*160, bijective
  int half = swz & 1;
  int hq = swz >> 1;
  int h = hq >> 5, qblk = hq & 31;
  int tid = threadIdx.x;
  int w = tid >> 6, l = tid & 63;
  int lr = l & 15, lg = l >> 4;

  const char* kch = (const char*)(kc + (size_t)h * S_LEN * HD);
  const short* vth = vtg + (size_t)h * DV * S_LEN;

  // Q frags (B operand): lane lr = q-row, pre-scaled by 2^-4
  int qrow = qblk * 64 + w * 16 + lr;
  const short* qbase = q + (size_t)qrow * Q_N + h * HD;
  bf16x8 qf[8];
#pragma unroll
  for (int kk = 0; kk < 8; ++kk) {
    bf16x8 v = *(const bf16x8*)(qbase + kk * 32 + lg * 8);
#pragma unroll
    for (int j = 0; j < 8; ++j) v[j] = f2bs(bs2f(v[j]) * 0.0625f);
    qf[kk] = v;
  }

  f32x4 acc[16] = {};      // lane lr = d-col, rows lg*4+r = q-rows
  float m = -3e38f;        // running max for q = lr
  float lsum = 0.f;

  for (int kb = half * 32; kb < half * 32 + 32; ++kb) {
    int key0 = kb * 32;
    // ---- stage K[32][256] and V^T[256][32] (gload_lds, swizzled source) ----
#pragma unroll
    for (int p = 0; p < 4; ++p) {
      int c = p * 256 + tid;
      int row = c >> 5;
      int sb = ((c & 31) * 16) ^ ((row & 7) << 4);
      gload16(kch + (size_t)(key0 + row) * 512 + sb, (char*)ks + c * 16);
    }
#pragma unroll
    for (int p = 0; p < 4; ++p) {
      int c = p * 256 + tid;
      int d = c >> 2, slot = c & 3;
      int dk = (d ^ (d >> 2)) & 3;
      gload16(vth + (size_t)d * S_LEN + key0 + (slot ^ dk) * 8, (char*)vt + c * 16);
    }
    WAIT_VM0();
    __builtin_amdgcn_s_barrier();

    // ---- QK^T swapped: s0 rows = keys 0..15, s1 rows = keys 16..31; col = q ----
    f32x4 s0 = {}, s1 = {};
    __builtin_amdgcn_s_setprio(1);
#pragma unroll
    for (int kk = 0; kk < 8; ++kk) {
      int cb = kk * 64 + lg * 16;
      int sw = (lr & 7) << 4;
      bf16x8 k0 = *(const bf16x8*)((const char*)ks + lr * 512 + (cb ^ sw));
      bf16x8 k1 = *(const bf16x8*)((const char*)ks + (16 + lr) * 512 + (cb ^ sw));
      s0 = __builtin_amdgcn_mfma_f32_16x16x32_bf16(k0, qf[kk], s0, 0, 0, 0);
      s1 = __builtin_amdgcn_mfma_f32_16x16x32_bf16(k1, qf[kk], s1, 0, 0, 0);
    }
    __builtin_amdgcn_s_setprio(0);

    // ---- softmax (all 8 scores belong to q = lr) ----
    float mx = fmaxf(fmaxf(fmaxf(s0[0], s0[1]), fmaxf(s0[2], s0[3])),
                     fmaxf(fmaxf(s1[0], s1[1]), fmaxf(s1[2], s1[3])));
    mx = fmaxf(mx, __shfl_xor(mx, 16));
    mx = fmaxf(mx, __shfl_xor(mx, 32));
    bool grow = mx > m + 8.f;
    if (__any((int)grow)) {
      float mn = fmaxf(m, mx);
      float co = __expf(m - mn);
      m = mn;
      lsum *= co;
      float c0 = __shfl(co, (l & 48) | (lg * 4 + 0));
      float c1 = __shfl(co, (l & 48) | (lg * 4 + 1));
      float c2 = __shfl(co, (l & 48) | (lg * 4 + 2));
      float c3 = __shfl(co, (l & 48) | (lg * 4 + 3));
#pragma unroll
      for (int t = 0; t < 16; ++t) {
        acc[t][0] *= c0; acc[t][1] *= c1; acc[t][2] *= c2; acc[t][3] *= c3;
      }
    }
    float e0 = __expf(s0[0] - m), e1 = __expf(s0[1] - m);
    float e2 = __expf(s0[2] - m), e3 = __expf(s0[3] - m);
    float e4 = __expf(s1[0] - m), e5 = __expf(s1[1] - m);
    float e6 = __expf(s1[2] - m), e7 = __expf(s1[3] - m);
    float ts = ((e0 + e1) + (e2 + e3)) + ((e4 + e5) + (e6 + e7));
    ts += __shfl_xor(ts, 16);
    ts += __shfl_xor(ts, 32);
    lsum += ts;
    bf16x8 pa;
    pa[0] = f2bs(e0); pa[1] = f2bs(e1); pa[2] = f2bs(e2); pa[3] = f2bs(e3);
    pa[4] = f2bs(e4); pa[5] = f2bs(e5); pa[6] = f2bs(e6); pa[7] = f2bs(e7);

    // ---- PV: acc[t] += P(A) * Vperm(B); dk = (d^(d>>2))&3 is lane-constant ----
    __builtin_amdgcn_s_setprio(1);
    int dk = (lr & 3) ^ ((lr >> 2) & 3);
#pragma unroll
    for (int t = 0; t < 16; ++t) {
      int d = t * 16 + lr;
      const char* vrow = (const char*)vt + d * 64 + (lg & 1) * 8;
      bf16x4 lo = *(const bf16x4*)(vrow + (((lg >> 1) ^ dk) << 4));
      bf16x4 hi = *(const bf16x4*)(vrow + ((((lg >> 1) + 2) ^ dk) << 4));
      bf16x8 vf = __builtin_shufflevector(lo, hi, 0, 1, 2, 3, 4, 5, 6, 7);
      acc[t] = __builtin_amdgcn_mfma_f32_16x16x32_bf16(pa, vf, acc[t], 0, 0, 0);
    }
    __builtin_amdgcn_s_setprio(0);
    WAIT_LGKM0();
    __builtin_amdgcn_s_barrier();   // all waves done reading ks/vt
  }

  // ---- write fp32 partials (no normalization; combine kernel merges halves) ----
  size_t probase = ((size_t)(half * NH + h) * S_LEN + qblk * 64);
#pragma unroll
  for (int t = 0; t < 16; ++t) {
    float* pp = pacc + (probase + w * 16 + lg * 4) * 256 + t * 16 + lr;
    pp[0] = acc[t][0]; pp[256] = acc[t][1]; pp[512] = acc[t][2]; pp[768] = acc[t][3];
  }
  if (lg == 0) {
    pm[probase + w * 16 + lr] = m;
    pl[probase + w * 16 + lr] = lsum;
  }
}

// ---------------- combine split-K partials -> bf16 attention output ----------------
// grid = S*NH*DV/(8*256); thread handles 8 d of one (h,row)
__global__ __launch_bounds__(256) void combine_kernel(const float* __restrict__ pacc,
                                                      const float* __restrict__ pm,
                                                      const float* __restrict__ pl,
                                                      short* __restrict__ ao) {
  int gt = blockIdx.x * 256 + threadIdx.x;
  int dg = gt & 31;
  int rh = gt >> 5;              // h*2048 + row
  int h = rh >> 11, row = rh & 2047;
  size_t i1 = (size_t)h * S_LEN + row;
  size_t i2 = (size_t)(NH + h) * S_LEN + row;
  float m1 = pm[i1], m2 = pm[i2];
  float l1 = pl[i1], l2 = pl[i2];
  float M = fmaxf(m1, m2);
  float e1 = __expf(m1 - M), e2 = __expf(m2 - M);
  float inv = 1.f / (e1 * l1 + e2 * l2);
  float w1 = e1 * inv, w2 = e2 * inv;
  const float* a1 = pacc + i1 * 256 + dg * 8;
  const float* a2 = pacc + i2 * 256 + dg * 8;
  f32x4 x1a = *(const f32x4*)a1, x1b = *(const f32x4*)(a1 + 4);
  f32x4 x2a = *(const f32x4*)a2, x2b = *(const f32x4*)(a2 + 4);
  bf16x8 r;
#pragma unroll
  for (int j = 0; j < 4; ++j) r[j] = f2bs(x1a[j] * w1 + x2a[j] * w2);
#pragma unroll
  for (int j = 0; j < 4; ++j) r[4 + j] = f2bs(x1b[j] * w1 + x2b[j] * w2);
  *(bf16x8*)(ao + (size_t)row * O_N + h * DV + dg * 8) = r;
}

extern "C" void kernel_launch(void* const* d_in, const int* in_sizes, int n_in,
                              void* d_out, int out_size, void* d_ws, size_t ws_size,
                              hipStream_t stream) {
  const float* x       = (const float*)d_in[0];
  const int*   pos     = (const int*)d_in[1];
  const float* q_a_w   = (const float*)d_in[2];
  const float* q_b_w   = (const float*)d_in[3];
  const float* kv_a_w  = (const float*)d_in[4];
  const float* kv_b_w  = (const float*)d_in[5];
  const float* o_w     = (const float*)d_in[6];
  const float* q_a_ln  = (const float*)d_in[7];
  const float* kv_a_ln = (const float*)d_in[8];
  float* out = (float*)d_out;

  char* base = (char*)d_ws;
  auto align256 = [](size_t v) { return (v + 255) & ~(size_t)255; };
  // ---- group A: buffers fully dead before attn6 runs (aliased by pacc) ----
  size_t offA = 0;
  auto allocA = [&](size_t bytes) { char* r = base + offA; offA = align256(offA + bytes); return r; };
  short* xb    = (short*)allocA((size_t)S_LEN * HID * 2);
  short* wcat  = (short*)allocA((size_t)QKVA * HID * 2);
  short* qbw   = (short*)allocA((size_t)Q_N * QR * 2);
  short* kvbw  = (short*)allocA((size_t)KV_N * KVR * 2);
  float* qkv   = (float*)allocA((size_t)S_LEN * QKVA * 4);
  short* q_ln  = (short*)allocA((size_t)S_LEN * QR * 2);
  short* kv_ln = (short*)allocA((size_t)S_LEN * KVR * 2);
  short* kvx   = (short*)allocA((size_t)S_LEN * KV_N * 2);
  short* kr    = (short*)allocA((size_t)S_LEN * 64 * 2);
  float* ct    = (float*)allocA((size_t)S_LEN * 32 * 4);
  float* st    = (float*)allocA((size_t)S_LEN * 32 * 4);
  float* pacc  = (float*)base;  // aliases group A (written only by attn6, after all A-readers)
  size_t paccB = (size_t)2 * NH * S_LEN * 256 * 4;  // 80MB
  size_t offB = align256(offA > paccB ? offA : paccB);
  auto allocB = [&](size_t bytes) { char* r = base + offB; offB = align256(offB + bytes); return r; };
  short* qbuf  = (short*)allocB((size_t)S_LEN * Q_N * 2);
  short* kcb   = (short*)allocB((size_t)NH * S_LEN * HD * 2);
  short* vtg   = (short*)allocB((size_t)NH * DV * S_LEN * 2);
  short* ao    = (short*)allocB((size_t)S_LEN * O_N * 2);
  short* ow    = (short*)allocB((size_t)HID * O_N * 2);
  float* pm    = (float*)allocB((size_t)2 * NH * S_LEN * 4);
  float* pl    = (float*)allocB((size_t)2 * NH * S_LEN * 4);
  (void)ws_size; (void)n_in; (void)in_sizes; (void)out_size;

  auto cvt = [&](const float* in, short* o, size_t n) {
    size_t blocks = (n + 255) / 256;
    if (blocks > 2048) blocks = 2048;
    f2b_kernel<<<dim3((unsigned)blocks), dim3(256), 0, stream>>>(in, o, n);
  };
  cvt(x, xb, (size_t)S_LEN * HID);
  cvt(q_a_w, wcat, (size_t)QR * HID);
  cvt(kv_a_w, wcat + (size_t)QR * HID, (size_t)KVA_N * HID);
  hipMemsetAsync(wcat + (size_t)(QR + KVA_N) * HID, 0, (size_t)(KVAP - KVA_N) * HID * 2, stream);
  cvt(q_b_w, qbw, (size_t)Q_N * QR);
  cvt(kv_b_w, kvbw, (size_t)KV_N * KVR);
  cvt(o_w, ow, (size_t)HID * O_N);

  dim3 blk(256);
  // fused a-proj: qkv[S][1408] = x @ [q_a_w ‖ kv_a_w]^T
  gemm64<<<dim3(QKVA / 128, S_LEN / 64), blk, 0, stream>>>(xb, wcat, qkv, S_LEN, QKVA, HID);
  // rmsnorms -> bf16
  rmsnorm_kernel<<<dim3(S_LEN), blk, 0, stream>>>(qkv, q_a_ln, q_ln, QR, QKVA, QR);
  rmsnorm_kernel<<<dim3(S_LEN), blk, 0, stream>>>(qkv + QR, kv_a_ln, kv_ln, KVR, QKVA, KVR);
  // up-projections -> bf16
  gemm128<1><<<dim3(Q_N / 128, S_LEN / 128), blk, 0, stream>>>(q_ln, qbw, qbuf, S_LEN, Q_N, QR);
  gemm128<1><<<dim3(KV_N / 128, S_LEN / 128), blk, 0, stream>>>(kv_ln, kvbw, kvx, S_LEN, KV_N, KVR);
  // rope
  rope_table_kernel<<<dim3(S_LEN / 256), blk, 0, stream>>>(pos, ct, st);
  rope_q_kernel<<<dim3((S_LEN * NH + 255) / 256), blk, 0, stream>>>(qbuf, ct, st);
  rope_k_kernel<<<dim3(S_LEN / 256), blk, 0, stream>>>(qkv + QR + KVR, ct, st, kr);
  // per-head contiguous K and transposed V
  kc_build<<<dim3(NH * S_LEN * 32 / 256), blk, 0, stream>>>(kvx, kr, kcb);
  vtrans<<<dim3(S_LEN / 64, DV / 64, NH), blk, 0, stream>>>(kvx, vtg);
  // fused attention, split-K=2 (pacc aliases group A — all dead by now)
  attn6<<<dim3(2 * NH * S_LEN / 64), blk, 0, stream>>>(qbuf, kcb, vtg, pacc, pm, pl);
  combine_kernel<<<dim3(S_LEN * NH * DV / (8 * 256)), blk, 0, stream>>>(pacc, pm, pl, ao);
  // output projection (fp32 out)
  gemm128<0><<<dim3(HID / 128, S_LEN / 128), blk, 0, stream>>>(ao, ow, out, S_LEN, HID, O_N);
}